// Round 9
// baseline (230.978 us; speedup 1.0000x reference)
//
#include <hip/hip_runtime.h>
#include <math.h>

typedef short bf16x8 __attribute__((ext_vector_type(8)));
typedef float f32x4  __attribute__((ext_vector_type(4)));

__device__ __forceinline__ unsigned short f2bf(float f) {
    union { float f; unsigned u; } v; v.f = f;
    unsigned r = v.u + 0x7FFFu + ((v.u >> 16) & 1u);   // RNE
    return (unsigned short)(r >> 16);
}

// async global->LDS, 16B per lane, LDS dest = wave-uniform base + lane*16B
#define GLDS16(gp, lp) __builtin_amdgcn_global_load_lds( \
    (const __attribute__((address_space(1))) void*)(gp), \
    (__attribute__((address_space(3))) void*)(lp), 16, 0, 0)

// Head-dim permutation: MFMA-C position (nt*16+c) stored at byte position
// (c*4+nt) within each 64-wide head block. Q,K share pi (dot invariant);
// V/Ab use sigma; Wto compensates.

// ---------------------------------------------------------------------------
// prep: z<4 -> W fp32 [k][n] -> Wt bf16 [n][k] (z=3 un-permutes sigma(pi));
//       z>=4 -> X fp32 -> bf16 copy-convert
// ---------------------------------------------------------------------------
__global__ __launch_bounds__(256)
void prep(const float* __restrict__ X, unsigned short* __restrict__ Xb,
          const float* __restrict__ w0, const float* __restrict__ w1,
          const float* __restrict__ w2, const float* __restrict__ w3,
          unsigned short* o0, unsigned short* o1,
          unsigned short* o2, unsigned short* o3)
{
    const int z = blockIdx.z;
    if (z >= 4) {
        const int lb = (z - 4) * 256 + blockIdx.y * 16 + blockIdx.x;
        const size_t t = (size_t)lb * 256 + threadIdx.x;
        const float4 a = *(const float4*)(X + t * 8);
        const float4 b = *(const float4*)(X + t * 8 + 4);
        unsigned short u[8] = { f2bf(a.x), f2bf(a.y), f2bf(a.z), f2bf(a.w),
                                f2bf(b.x), f2bf(b.y), f2bf(b.z), f2bf(b.w) };
        *(int4*)(Xb + t * 8) = *(int4*)u;
        return;
    }
    const float* W; unsigned short* O;
    switch (z) {
        case 0: W = w0; O = o0; break;
        case 1: W = w1; O = o1; break;
        case 2: W = w2; O = o2; break;
        default: W = w3; O = o3; break;
    }
    __shared__ float T[64][65];
    const int tid = threadIdx.x;
    const int n0 = blockIdx.x * 64, k0 = blockIdx.y * 64;
    #pragma unroll
    for (int i = 0; i < 4; i++) {
        const int k = (tid >> 4) + i * 16, n4 = (tid & 15) * 4;
        const float4 v = *(const float4*)(W + (size_t)(k0 + k) * 1024 + n0 + n4);
        T[k][n4] = v.x; T[k][n4+1] = v.y; T[k][n4+2] = v.z; T[k][n4+3] = v.w;
    }
    __syncthreads();
    if (z == 3) {
        #pragma unroll
        for (int i = 0; i < 4; i++) {
            const int n = (tid >> 4) + i * 16, k4 = (tid & 15) * 4;
            unsigned short u[4];
            #pragma unroll
            for (int j = 0; j < 4; j++) {
                const int q = k4 + j;                      // Ab storage pos
                const int p = (q & 3) * 16 + (q >> 2);     // inv sigma
                const int d = (p & 3) * 16 + (p >> 2);     // inv pi
                u[j] = f2bf(T[d][n]);
            }
            *(int2*)(O + (size_t)(n0 + n) * 1024 + k0 + k4) = *(int2*)u;
        }
    } else {
        #pragma unroll
        for (int i = 0; i < 4; i++) {
            const int n = (tid >> 4) + i * 16, k4 = (tid & 15) * 4;
            unsigned short u[4] = { f2bf(T[k4][n]), f2bf(T[k4+1][n]),
                                    f2bf(T[k4+2][n]), f2bf(T[k4+3][n]) };
            *(int2*)(O + (size_t)(n0 + n) * 1024 + k0 + k4) = *(int2*)u;
        }
    }
}

// ---------------------------------------------------------------------------
// QKV GEMM, BK=64 as two 32-col panels (64B LDS pitch preserved for
// conflict-free frag reads; half the barriers). Epilogue: q/k -> bias + RoPE
// (HW sin/cos) + pi-packed b64 stores; v -> bias + DIRECT V^T [bh][p][s]
// write (C-layout regs = 4 consecutive s -> natural b64 pack).
// ---------------------------------------------------------------------------
__global__ __launch_bounds__(256)
void qkv_gemm(const unsigned short* __restrict__ Xb,
              const unsigned short* __restrict__ Wtq, const unsigned short* __restrict__ Wtk,
              const unsigned short* __restrict__ Wtv,
              const float* __restrict__ bq, const float* __restrict__ bk,
              const float* __restrict__ bv,
              unsigned short* __restrict__ Qb, unsigned short* __restrict__ Kb,
              unsigned short* __restrict__ Vtb)
{
    const unsigned short* Wt; const float* bias; unsigned short* Out;
    const int z = blockIdx.z;
    if (z == 0)      { Wt = Wtq; bias = bq; Out = Qb; }
    else if (z == 1) { Wt = Wtk; bias = bk; Out = Kb; }
    else             { Wt = Wtv; bias = bv; Out = Vtb; }

    __shared__ unsigned short As0[128 * 32], As1[128 * 32];  // pitch 64B
    __shared__ unsigned short Bs0[128 * 32], Bs1[128 * 32];
    const int tid = threadIdx.x, lane = tid & 63, w = tid >> 6;
    const int quad = lane >> 4, c = lane & 15;
    const int wr = w >> 1, wc = w & 1;
    const int m0 = blockIdx.x * 128, n0 = blockIdx.y * 128;
    const int srow = lane >> 2, scol = (lane & 3) * 8;

    f32x4 acc[4][4];
    #pragma unroll
    for (int i = 0; i < 4; i++)
        #pragma unroll
        for (int j = 0; j < 4; j++) acc[i][j] = (f32x4){0.f, 0.f, 0.f, 0.f};

    for (int k0 = 0; k0 < 1024; k0 += 64) {
        #pragma unroll
        for (int j = 0; j < 2; j++) {
            const int r = w * 32 + j * 16;
            const size_t ga = (size_t)(m0 + r + srow) * 1024 + k0 + scol;
            const size_t gb = (size_t)(n0 + r + srow) * 1024 + k0 + scol;
            GLDS16(Xb + ga,      &As0[r * 32]);
            GLDS16(Xb + ga + 32, &As1[r * 32]);
            GLDS16(Wt + gb,      &Bs0[r * 32]);
            GLDS16(Wt + gb + 32, &Bs1[r * 32]);
        }
        __syncthreads();
        bf16x8 af0[4], af1[4], bf0[4], bf1[4];
        #pragma unroll
        for (int rt = 0; rt < 4; rt++) {
            const int ro = (wr * 64 + rt * 16 + c) * 32 + quad * 8;
            af0[rt] = *(const bf16x8*)&As0[ro];
            af1[rt] = *(const bf16x8*)&As1[ro];
        }
        #pragma unroll
        for (int nt = 0; nt < 4; nt++) {
            const int ro = (wc * 64 + nt * 16 + c) * 32 + quad * 8;
            bf0[nt] = *(const bf16x8*)&Bs0[ro];
            bf1[nt] = *(const bf16x8*)&Bs1[ro];
        }
        #pragma unroll
        for (int rt = 0; rt < 4; rt++)
            #pragma unroll
            for (int nt = 0; nt < 4; nt++) {
                acc[rt][nt] = __builtin_amdgcn_mfma_f32_16x16x32_bf16(af0[rt], bf0[nt], acc[rt][nt], 0, 0, 0);
                acc[rt][nt] = __builtin_amdgcn_mfma_f32_16x16x32_bf16(af1[rt], bf1[nt], acc[rt][nt], 0, 0, 0);
            }
        __syncthreads();
    }

    const int h = (n0 + wc * 64) >> 6;
    float bv4[4];
    #pragma unroll
    for (int nt = 0; nt < 4; nt++) bv4[nt] = bias[n0 + wc * 64 + nt * 16 + c];

    if (z == 2) {
        // V: direct transposed write [bh][p][s], p = sigma(d) = c*4+nt
        #pragma unroll
        for (int rt = 0; rt < 4; rt++) {
            const int s0g = m0 + wr * 64 + rt * 16 + quad * 4;
            const int b = s0g >> 11, s = s0g & 2047;
            unsigned short* dstb = Out + (size_t)(b * 16 + h) * 64 * 2048;
            #pragma unroll
            for (int nt = 0; nt < 4; nt++) {
                unsigned short u[4];
                #pragma unroll
                for (int reg = 0; reg < 4; reg++) u[reg] = f2bf(acc[rt][nt][reg] + bv4[nt]);
                *(int2*)(dstb + (size_t)(c * 4 + nt) * 2048 + s) = *(int2*)u;
            }
        }
        return;
    }

    const float kLn = 9.210340371976184f / 32.0f;   // ln(10000)/32
    const float TWO_PI_INV = 0.15915494309189535f;
    const float rv0 = expf(-(float)c * kLn) * TWO_PI_INV;
    const float rv1 = expf(-(float)(c + 16) * kLn) * TWO_PI_INV;

    #pragma unroll
    for (int rt = 0; rt < 4; rt++) {
        #pragma unroll
        for (int reg = 0; reg < 4; reg++) {
            const int m = m0 + wr * 64 + rt * 16 + quad * 4 + reg;
            const int b = m >> 11, s = m & 2047;
            float x0 = acc[rt][0][reg] + bv4[0];
            float x1 = acc[rt][1][reg] + bv4[1];
            float x2 = acc[rt][2][reg] + bv4[2];
            float x3 = acc[rt][3][reg] + bv4[3];
            float r0 = (float)s * rv0;  r0 -= floorf(r0);
            float r1 = (float)s * rv1;  r1 -= floorf(r1);
            const float sn0 = __builtin_amdgcn_sinf(r0);
            const float cs0 = __builtin_amdgcn_cosf(r0);
            const float sn1 = __builtin_amdgcn_sinf(r1);
            const float cs1 = __builtin_amdgcn_cosf(r1);
            const float y0 = x0 * cs0 - x2 * sn0, y2 = x0 * sn0 + x2 * cs0;
            const float y1 = x1 * cs1 - x3 * sn1, y3 = x1 * sn1 + x3 * cs1;
            unsigned short u[4] = { f2bf(y0), f2bf(y1), f2bf(y2), f2bf(y3) };
            unsigned short* dst = Out + ((size_t)(b * 16 + h) * 2048 + s) * 64;
            *(int2*)(dst + c * 4) = *(int2*)u;     // pi: pos c*4+nt
        }
    }
}

// ---------------------------------------------------------------------------
// Output projection GEMM, BK=64 two-panel staging + bias -> fp32 d_out
// ---------------------------------------------------------------------------
__global__ __launch_bounds__(256)
void out_gemm(const unsigned short* __restrict__ Ab, const unsigned short* __restrict__ Wto,
              const float* __restrict__ bo, float* __restrict__ Out)
{
    __shared__ unsigned short As0[128 * 32], As1[128 * 32];
    __shared__ unsigned short Bs0[128 * 32], Bs1[128 * 32];
    const int tid = threadIdx.x, lane = tid & 63, w = tid >> 6;
    const int quad = lane >> 4, c = lane & 15;
    const int wr = w >> 1, wc = w & 1;
    const int m0 = blockIdx.x * 128, n0 = blockIdx.y * 128;
    const int srow = lane >> 2, scol = (lane & 3) * 8;

    f32x4 acc[4][4];
    #pragma unroll
    for (int i = 0; i < 4; i++)
        #pragma unroll
        for (int j = 0; j < 4; j++) acc[i][j] = (f32x4){0.f, 0.f, 0.f, 0.f};

    for (int k0 = 0; k0 < 1024; k0 += 64) {
        #pragma unroll
        for (int j = 0; j < 2; j++) {
            const int r = w * 32 + j * 16;
            const size_t ga = (size_t)(m0 + r + srow) * 1024 + k0 + scol;
            const size_t gb = (size_t)(n0 + r + srow) * 1024 + k0 + scol;
            GLDS16(Ab  + ga,      &As0[r * 32]);
            GLDS16(Ab  + ga + 32, &As1[r * 32]);
            GLDS16(Wto + gb,      &Bs0[r * 32]);
            GLDS16(Wto + gb + 32, &Bs1[r * 32]);
        }
        __syncthreads();
        bf16x8 af0[4], af1[4], bf0[4], bf1[4];
        #pragma unroll
        for (int rt = 0; rt < 4; rt++) {
            const int ro = (wr * 64 + rt * 16 + c) * 32 + quad * 8;
            af0[rt] = *(const bf16x8*)&As0[ro];
            af1[rt] = *(const bf16x8*)&As1[ro];
        }
        #pragma unroll
        for (int nt = 0; nt < 4; nt++) {
            const int ro = (wc * 64 + nt * 16 + c) * 32 + quad * 8;
            bf0[nt] = *(const bf16x8*)&Bs0[ro];
            bf1[nt] = *(const bf16x8*)&Bs1[ro];
        }
        #pragma unroll
        for (int rt = 0; rt < 4; rt++)
            #pragma unroll
            for (int nt = 0; nt < 4; nt++) {
                acc[rt][nt] = __builtin_amdgcn_mfma_f32_16x16x32_bf16(af0[rt], bf0[nt], acc[rt][nt], 0, 0, 0);
                acc[rt][nt] = __builtin_amdgcn_mfma_f32_16x16x32_bf16(af1[rt], bf1[nt], acc[rt][nt], 0, 0, 0);
            }
        __syncthreads();
    }
    #pragma unroll
    for (int rt = 0; rt < 4; rt++) {
        #pragma unroll
        for (int reg = 0; reg < 4; reg++) {
            const int m = m0 + wr * 64 + rt * 16 + quad * 4 + reg;
            #pragma unroll
            for (int nt = 0; nt < 4; nt++) {
                const int n = n0 + wc * 64 + nt * 16 + c;
                Out[(size_t)m * 1024 + n] = acc[rt][nt][reg] + bo[n];
            }
        }
    }
}

// ---------------------------------------------------------------------------
// Split-K flash attention (R6/R8 structure, unchanged).
// ---------------------------------------------------------------------------
__global__ __launch_bounds__(256)
void attn_part(const unsigned short* __restrict__ Qb, const unsigned short* __restrict__ Kb,
               const unsigned short* __restrict__ Vtb, unsigned short* __restrict__ Ab,
               float* __restrict__ Opart, float* __restrict__ Lpart)
{
    __shared__ unsigned short Ks[64 * 72];      // [key][d], pitch 144B
    __shared__ unsigned short Vs[65 * 72];      // [p][key] + ones row
    __shared__ unsigned short Ps[4 * 16 * 72];  // per-wave P [q][key]

    const int tid = threadIdx.x, w = tid >> 6, lane = tid & 63;
    const int quad = lane >> 4, c = lane & 15;
    const int bh = blockIdx.y;
    const int x = (blockIdx.x < 32) ? (int)blockIdx.x + 16 : (int)blockIdx.x - 32;
    int i, start, len;
    if (x < 32) { i = x + 1;  start = 0;  len = (i < 16) ? i : 16; }
    else        { i = x - 15; start = 16; len = i - 16; }
    const int q0 = (i - 1) * 64;
    const bool complete = (start == 0) && (len == i);
    const size_t base = (size_t)bh * 2048 * 64;

    if (tid < 64) Vs[64 * 72 + tid] = 0x3F80;   // bf16 1.0 ones row

    const int qbase = q0 + w * 16;
    const int qrow  = qbase + c;
    const size_t qoff = base + (size_t)qrow * 64;
    const bf16x8 qf0 = *(const bf16x8*)(Qb + qoff + quad * 8);
    const bf16x8 qf1 = *(const bf16x8*)(Qb + qoff + 32 + quad * 8);

    f32x4 O[4], Osum;
    Osum = (f32x4){0.f, 0.f, 0.f, 0.f};
    #pragma unroll
    for (int nt = 0; nt < 4; nt++) O[nt] = (f32x4){0.f, 0.f, 0.f, 0.f};

    const int r0s = tid >> 3, r1s = r0s + 32, c8 = (tid & 7) * 8;

    int k0 = start * 64;
    int4 kreg0 = *(const int4*)(Kb  + base + (size_t)(k0 + r0s) * 64 + c8);
    int4 kreg1 = *(const int4*)(Kb  + base + (size_t)(k0 + r1s) * 64 + c8);
    int4 vreg0 = *(const int4*)(Vtb + base + (size_t)r0s * 2048 + k0 + c8);
    int4 vreg1 = *(const int4*)(Vtb + base + (size_t)r1s * 2048 + k0 + c8);

    unsigned short* Pw = Ps + w * 16 * 72;

    for (int t = 0; t < len; t++, k0 += 64) {
        *(int4*)&Ks[(size_t)r0s * 72 + c8] = kreg0;
        *(int4*)&Ks[(size_t)r1s * 72 + c8] = kreg1;
        *(int4*)&Vs[(size_t)r0s * 72 + c8] = vreg0;
        *(int4*)&Vs[(size_t)r1s * 72 + c8] = vreg1;
        __syncthreads();

        if (t + 1 < len) {
            const int kn = k0 + 64;
            kreg0 = *(const int4*)(Kb  + base + (size_t)(kn + r0s) * 64 + c8);
            kreg1 = *(const int4*)(Kb  + base + (size_t)(kn + r1s) * 64 + c8);
            vreg0 = *(const int4*)(Vtb + base + (size_t)r0s * 2048 + kn + c8);
            vreg1 = *(const int4*)(Vtb + base + (size_t)r1s * 2048 + kn + c8);
        }

        const bool need_mask = (k0 + 63) > qbase;

        #pragma unroll
        for (int nt = 0; nt < 4; nt++) {
            const bf16x8 kf0 = *(const bf16x8*)&Ks[(nt * 16 + c) * 72 + quad * 8];
            const bf16x8 kf1 = *(const bf16x8*)&Ks[(nt * 16 + c) * 72 + 32 + quad * 8];
            f32x4 s4 = (f32x4){0.f, 0.f, 0.f, 0.f};
            s4 = __builtin_amdgcn_mfma_f32_16x16x32_bf16(kf0, qf0, s4, 0, 0, 0);
            s4 = __builtin_amdgcn_mfma_f32_16x16x32_bf16(kf1, qf1, s4, 0, 0, 0);
            const int keyb = k0 + nt * 16 + quad * 4;
            unsigned short u[4];
            #pragma unroll
            for (int reg = 0; reg < 4; reg++) {
                float p = __expf(s4[reg] * 0.125f);
                if (need_mask && (keyb + reg > qrow)) p = 0.f;
                u[reg] = f2bf(p);
            }
            *(int2*)&Pw[c * 72 + nt * 16 + quad * 4] = *(int2*)u;
        }

        const bf16x8 pa0 = *(const bf16x8*)&Pw[c * 72 + quad * 8];
        const bf16x8 pa1 = *(const bf16x8*)&Pw[c * 72 + 32 + quad * 8];
        #pragma unroll
        for (int nt = 0; nt < 4; nt++) {
            const bf16x8 vb0 = *(const bf16x8*)&Vs[(nt * 16 + c) * 72 + quad * 8];
            const bf16x8 vb1 = *(const bf16x8*)&Vs[(nt * 16 + c) * 72 + 32 + quad * 8];
            O[nt] = __builtin_amdgcn_mfma_f32_16x16x32_bf16(pa0, vb0, O[nt], 0, 0, 0);
            O[nt] = __builtin_amdgcn_mfma_f32_16x16x32_bf16(pa1, vb1, O[nt], 0, 0, 0);
        }
        const bf16x8 on0 = *(const bf16x8*)&Vs[64 * 72 + quad * 8];
        const bf16x8 on1 = *(const bf16x8*)&Vs[64 * 72 + 32 + quad * 8];
        Osum = __builtin_amdgcn_mfma_f32_16x16x32_bf16(pa0, on0, Osum, 0, 0, 0);
        Osum = __builtin_amdgcn_mfma_f32_16x16x32_bf16(pa1, on1, Osum, 0, 0, 0);
        __syncthreads();
    }

    if (complete) {
        const int b = bh >> 4, h = bh & 15;
        #pragma unroll
        for (int reg = 0; reg < 4; reg++) {
            const float inv = 1.0f / Osum[reg];
            const int q = qbase + quad * 4 + reg;
            unsigned short u[4];
            #pragma unroll
            for (int nt = 0; nt < 4; nt++) u[nt] = f2bf(O[nt][reg] * inv);
            unsigned short* dst = Ab + ((size_t)(b * 2048 + q)) * 1024 + h * 64;
            *(int2*)(dst + c * 4) = *(int2*)u;     // sigma: pos c*4+nt
        }
    } else {
        const int pslot = (i - 17) * 2 + (start ? 1 : 0);
        float* Op = Opart + ((size_t)bh * 32 + pslot) * 4096;
        float* Lp = Lpart + ((size_t)bh * 32 + pslot) * 64;
        #pragma unroll
        for (int reg = 0; reg < 4; reg++) {
            const int row = w * 16 + quad * 4 + reg;
            float4 o4 = make_float4(O[0][reg], O[1][reg], O[2][reg], O[3][reg]);
            *(float4*)(Op + (size_t)row * 64 + c * 4) = o4;   // sigma order
            if (c == 0) Lp[row] = Osum[reg];
        }
    }
}

// ---------------------------------------------------------------------------
// Combine two partials: O = O0+O1, normalize, write bf16.
// ---------------------------------------------------------------------------
__global__ __launch_bounds__(256)
void attn_combine(const float* __restrict__ Opart, const float* __restrict__ Lpart,
                  unsigned short* __restrict__ Ab)
{
    const int tid = threadIdx.x;
    const int j = blockIdx.x, bh = blockIdx.y;
    const int q0 = (j + 16) * 64;
    const size_t s0 = ((size_t)bh * 32 + j * 2) * 4096;
    const size_t l0 = ((size_t)bh * 32 + j * 2) * 64;

    __shared__ float linv[64];
    if (tid < 64) linv[tid] = 1.0f / (Lpart[l0 + tid] + Lpart[l0 + 64 + tid]);
    __syncthreads();

    const int row = tid >> 2, col0 = (tid & 3) * 16;
    const float inv = linv[row];
    const int b = bh >> 4, h = bh & 15;
    const int q = q0 + row;
    unsigned short* dst = Ab + ((size_t)(b * 2048 + q)) * 1024 + h * 64 + col0;
    #pragma unroll
    for (int c4 = 0; c4 < 16; c4 += 4) {
        const float4 a  = *(const float4*)(Opart + s0 + (size_t)row * 64 + col0 + c4);
        const float4 bb = *(const float4*)(Opart + s0 + 4096 + (size_t)row * 64 + col0 + c4);
        dst[c4 + 0] = f2bf((a.x + bb.x) * inv);
        dst[c4 + 1] = f2bf((a.y + bb.y) * inv);
        dst[c4 + 2] = f2bf((a.z + bb.z) * inv);
        dst[c4 + 3] = f2bf((a.w + bb.w) * inv);
    }
}

// ---------------------------------------------------------------------------
extern "C" void kernel_launch(void* const* d_in, const int* in_sizes, int n_in,
                              void* d_out, int out_size, void* d_ws, size_t ws_size,
                              hipStream_t stream)
{
    const float* X  = (const float*)d_in[0];
    const float* wq = (const float*)d_in[2];
    const float* bq = (const float*)d_in[3];
    const float* wk = (const float*)d_in[4];
    const float* bk = (const float*)d_in[5];
    const float* wv = (const float*)d_in[6];
    const float* bv = (const float*)d_in[7];
    const float* wo = (const float*)d_in[8];
    const float* bo = (const float*)d_in[9];

    unsigned short* ws = (unsigned short*)d_ws;
    const size_t M1 = 1024 * 1024;
    unsigned short* Xb  = ws;             // 4M elems
    unsigned short* Wtq = Xb  + 4 * M1;   // 1M each
    unsigned short* Wtk = Wtq + M1;
    unsigned short* Wtv = Wtk + M1;
    unsigned short* Wto = Wtv + M1;
    unsigned short* Qb  = Wto + M1;       // 4M each
    unsigned short* Kb  = Qb  + 4 * M1;
    unsigned short* Vtb = Kb  + 4 * M1;   // V^T written directly by qkv_gemm
    unsigned short* Ab  = Vtb + 4 * M1;   // bf16, 4M elems
    float* Opart = (float*)(Ab + 4 * M1); // 16 MB
    float* Lpart = Opart + (size_t)32 * 32 * 4096;

    prep        <<<dim3(16, 16, 12), 256, 0, stream>>>(X, Xb, wq, wk, wv, wo,
                                                       Wtq, Wtk, Wtv, Wto);
    qkv_gemm    <<<dim3(32, 8, 3), 256, 0, stream>>>(Xb, Wtq, Wtk, Wtv, bq, bk, bv,
                                                     Qb, Kb, Vtb);
    attn_part   <<<dim3(48, 32), 256, 0, stream>>>(Qb, Kb, Vtb, Ab, Opart, Lpart);
    attn_combine<<<dim3(16, 32), 256, 0, stream>>>(Opart, Lpart, Ab);
    out_gemm    <<<dim3(32, 8), 256, 0, stream>>>(Ab, Wto, bo, (float*)d_out);
}

// Round 10
// 226.108 us; speedup vs baseline: 1.0215x; 1.0215x over previous
//
#include <hip/hip_runtime.h>
#include <math.h>

typedef short bf16x8 __attribute__((ext_vector_type(8)));
typedef float f32x4  __attribute__((ext_vector_type(4)));

__device__ __forceinline__ unsigned short f2bf(float f) {
    union { float f; unsigned u; } v; v.f = f;
    unsigned r = v.u + 0x7FFFu + ((v.u >> 16) & 1u);   // RNE
    return (unsigned short)(r >> 16);
}

// async global->LDS, 16B per lane, LDS dest = wave-uniform base + lane*16B
#define GLDS16(gp, lp) __builtin_amdgcn_global_load_lds( \
    (const __attribute__((address_space(1))) void*)(gp), \
    (__attribute__((address_space(3))) void*)(lp), 16, 0, 0)

// Head-dim permutation: MFMA-C position (nt*16+c) stored at byte position
// (c*4+nt) within each 64-wide head block. Q,K share pi (dot invariant);
// V/Ab use sigma; Wto compensates. Q additionally pre-scaled by 0.125.

// ---------------------------------------------------------------------------
// prep: z<4 -> W fp32 [k][n] -> Wt bf16 [n][k] (z=3 un-permutes sigma(pi));
//       z>=4 -> X fp32 -> bf16 copy-convert
// ---------------------------------------------------------------------------
__global__ __launch_bounds__(256)
void prep(const float* __restrict__ X, unsigned short* __restrict__ Xb,
          const float* __restrict__ w0, const float* __restrict__ w1,
          const float* __restrict__ w2, const float* __restrict__ w3,
          unsigned short* o0, unsigned short* o1,
          unsigned short* o2, unsigned short* o3)
{
    const int z = blockIdx.z;
    if (z >= 4) {
        const int lb = (z - 4) * 256 + blockIdx.y * 16 + blockIdx.x;
        const size_t t = (size_t)lb * 256 + threadIdx.x;
        const float4 a = *(const float4*)(X + t * 8);
        const float4 b = *(const float4*)(X + t * 8 + 4);
        unsigned short u[8] = { f2bf(a.x), f2bf(a.y), f2bf(a.z), f2bf(a.w),
                                f2bf(b.x), f2bf(b.y), f2bf(b.z), f2bf(b.w) };
        *(int4*)(Xb + t * 8) = *(int4*)u;
        return;
    }
    const float* W; unsigned short* O;
    switch (z) {
        case 0: W = w0; O = o0; break;
        case 1: W = w1; O = o1; break;
        case 2: W = w2; O = o2; break;
        default: W = w3; O = o3; break;
    }
    __shared__ float T[64][65];
    const int tid = threadIdx.x;
    const int n0 = blockIdx.x * 64, k0 = blockIdx.y * 64;
    #pragma unroll
    for (int i = 0; i < 4; i++) {
        const int k = (tid >> 4) + i * 16, n4 = (tid & 15) * 4;
        const float4 v = *(const float4*)(W + (size_t)(k0 + k) * 1024 + n0 + n4);
        T[k][n4] = v.x; T[k][n4+1] = v.y; T[k][n4+2] = v.z; T[k][n4+3] = v.w;
    }
    __syncthreads();
    if (z == 3) {
        #pragma unroll
        for (int i = 0; i < 4; i++) {
            const int n = (tid >> 4) + i * 16, k4 = (tid & 15) * 4;
            unsigned short u[4];
            #pragma unroll
            for (int j = 0; j < 4; j++) {
                const int q = k4 + j;                      // Ab storage pos
                const int p = (q & 3) * 16 + (q >> 2);     // inv sigma
                const int d = (p & 3) * 16 + (p >> 2);     // inv pi
                u[j] = f2bf(T[d][n]);
            }
            *(int2*)(O + (size_t)(n0 + n) * 1024 + k0 + k4) = *(int2*)u;
        }
    } else {
        #pragma unroll
        for (int i = 0; i < 4; i++) {
            const int n = (tid >> 4) + i * 16, k4 = (tid & 15) * 4;
            unsigned short u[4] = { f2bf(T[k4][n]), f2bf(T[k4+1][n]),
                                    f2bf(T[k4+2][n]), f2bf(T[k4+3][n]) };
            *(int2*)(O + (size_t)(n0 + n) * 1024 + k0 + k4) = *(int2*)u;
        }
    }
}

// ---------------------------------------------------------------------------
// QKV GEMM, BK=32 m97 staging. Epilogue: q -> bias+RoPE+0.125 prescale,
// k -> bias+RoPE, both pi-packed b64; v -> bias + V^T via LDS transpose
// (coalesced [p][s] stores). LDS aliased: staging 16KB / transpose 18.4KB.
// ---------------------------------------------------------------------------
__global__ __launch_bounds__(256)
void qkv_gemm(const unsigned short* __restrict__ Xb,
              const unsigned short* __restrict__ Wtq, const unsigned short* __restrict__ Wtk,
              const unsigned short* __restrict__ Wtv,
              const float* __restrict__ bq, const float* __restrict__ bk,
              const float* __restrict__ bv,
              unsigned short* __restrict__ Qb, unsigned short* __restrict__ Kb,
              unsigned short* __restrict__ Vtb)
{
    const unsigned short* Wt; const float* bias; unsigned short* Out;
    const int z = blockIdx.z;
    if (z == 0)      { Wt = Wtq; bias = bq; Out = Qb; }
    else if (z == 1) { Wt = Wtk; bias = bk; Out = Kb; }
    else             { Wt = Wtv; bias = bv; Out = Vtb; }

    __shared__ unsigned short Sh[128 * 72];          // 18.4 KB
    unsigned short* As = Sh;                         // 128*32 staging [m][k]
    unsigned short* Bs = Sh + 128 * 32;              // 128*32 staging [n][k]
    unsigned short* T  = Sh;                         // 128*72 epilogue transpose

    const int tid = threadIdx.x, lane = tid & 63, w = tid >> 6;
    const int quad = lane >> 4, c = lane & 15;
    const int wr = w >> 1, wc = w & 1;
    const int m0 = blockIdx.x * 128, n0 = blockIdx.y * 128;
    const int srow = lane >> 2, scol = (lane & 3) * 8;

    f32x4 acc[4][4];
    #pragma unroll
    for (int i = 0; i < 4; i++)
        #pragma unroll
        for (int j = 0; j < 4; j++) acc[i][j] = (f32x4){0.f, 0.f, 0.f, 0.f};

    for (int k0 = 0; k0 < 1024; k0 += 32) {
        #pragma unroll
        for (int j = 0; j < 2; j++) {
            const int r = w * 32 + j * 16;
            GLDS16(Xb + (size_t)(m0 + r + srow) * 1024 + k0 + scol, &As[r * 32]);
            GLDS16(Wt + (size_t)(n0 + r + srow) * 1024 + k0 + scol, &Bs[r * 32]);
        }
        __syncthreads();
        bf16x8 af[4], bf[4];
        #pragma unroll
        for (int rt = 0; rt < 4; rt++)
            af[rt] = *(const bf16x8*)&As[(wr * 64 + rt * 16 + c) * 32 + quad * 8];
        #pragma unroll
        for (int nt = 0; nt < 4; nt++)
            bf[nt] = *(const bf16x8*)&Bs[(wc * 64 + nt * 16 + c) * 32 + quad * 8];
        #pragma unroll
        for (int rt = 0; rt < 4; rt++)
            #pragma unroll
            for (int nt = 0; nt < 4; nt++)
                acc[rt][nt] = __builtin_amdgcn_mfma_f32_16x16x32_bf16(af[rt], bf[nt], acc[rt][nt], 0, 0, 0);
        __syncthreads();
    }

    float bv4[4];
    #pragma unroll
    for (int nt = 0; nt < 4; nt++) bv4[nt] = bias[n0 + wc * 64 + nt * 16 + c];

    if (z == 2) {
        // V: per-head LDS transpose then coalesced [p][s] stores
        const int b = m0 >> 11, sb = m0 & 2047;
        const int hgbase = n0 >> 6;
        #pragma unroll
        for (int h = 0; h < 2; h++) {
            if (wc == h) {
                #pragma unroll
                for (int rt = 0; rt < 4; rt++)
                    #pragma unroll
                    for (int reg = 0; reg < 4; reg++) {
                        const int s = wr * 64 + rt * 16 + quad * 4 + reg;
                        unsigned short u[4];
                        #pragma unroll
                        for (int nt = 0; nt < 4; nt++)
                            u[nt] = f2bf(acc[rt][nt][reg] + bv4[nt]);
                        *(int2*)&T[s * 72 + c * 4] = *(int2*)u;   // p = c*4+nt (sigma)
                    }
            }
            __syncthreads();
            const int p = tid >> 2, s8 = (tid & 3) * 32;
            unsigned short* dstb = Vtb + ((size_t)(b * 16 + hgbase + h) * 64 + p) * 2048 + sb;
            #pragma unroll
            for (int jj = 0; jj < 32; jj += 8) {
                unsigned short u[8];
                #pragma unroll
                for (int j = 0; j < 8; j++) u[j] = T[(s8 + jj + j) * 72 + p];
                *(int4*)(dstb + s8 + jj) = *(int4*)u;
            }
            __syncthreads();
        }
        return;
    }

    const float kLn = 9.210340371976184f / 32.0f;   // ln(10000)/32
    const float TWO_PI_INV = 0.15915494309189535f;
    const float rv0 = expf(-(float)c * kLn) * TWO_PI_INV;
    const float rv1 = expf(-(float)(c + 16) * kLn) * TWO_PI_INV;
    const float qscale = (z == 0) ? 0.125f : 1.0f;  // fold 1/sqrt(64) into Q

    #pragma unroll
    for (int rt = 0; rt < 4; rt++) {
        #pragma unroll
        for (int reg = 0; reg < 4; reg++) {
            const int m = m0 + wr * 64 + rt * 16 + quad * 4 + reg;
            const int b = m >> 11, s = m & 2047;
            float x0 = acc[rt][0][reg] + bv4[0];
            float x1 = acc[rt][1][reg] + bv4[1];
            float x2 = acc[rt][2][reg] + bv4[2];
            float x3 = acc[rt][3][reg] + bv4[3];
            float r0 = (float)s * rv0;  r0 -= floorf(r0);
            float r1 = (float)s * rv1;  r1 -= floorf(r1);
            const float sn0 = __builtin_amdgcn_sinf(r0);
            const float cs0 = __builtin_amdgcn_cosf(r0);
            const float sn1 = __builtin_amdgcn_sinf(r1);
            const float cs1 = __builtin_amdgcn_cosf(r1);
            const float y0 = (x0 * cs0 - x2 * sn0) * qscale;
            const float y2 = (x0 * sn0 + x2 * cs0) * qscale;
            const float y1 = (x1 * cs1 - x3 * sn1) * qscale;
            const float y3 = (x1 * sn1 + x3 * cs1) * qscale;
            const int h = (n0 + wc * 64) >> 6;
            unsigned short u[4] = { f2bf(y0), f2bf(y1), f2bf(y2), f2bf(y3) };
            unsigned short* dst = Out + ((size_t)(b * 16 + h) * 2048 + s) * 64;
            *(int2*)(dst + c * 4) = *(int2*)u;     // pi: pos c*4+nt
        }
    }
}

// ---------------------------------------------------------------------------
// Output projection GEMM (BK=32 m97 staging) + bias -> fp32 d_out
// ---------------------------------------------------------------------------
__global__ __launch_bounds__(256)
void out_gemm(const unsigned short* __restrict__ Ab, const unsigned short* __restrict__ Wto,
              const float* __restrict__ bo, float* __restrict__ Out)
{
    __shared__ unsigned short As[128 * 32];
    __shared__ unsigned short Bs[128 * 32];
    const int tid = threadIdx.x, lane = tid & 63, w = tid >> 6;
    const int quad = lane >> 4, c = lane & 15;
    const int wr = w >> 1, wc = w & 1;
    const int m0 = blockIdx.x * 128, n0 = blockIdx.y * 128;
    const int srow = lane >> 2, scol = (lane & 3) * 8;

    f32x4 acc[4][4];
    #pragma unroll
    for (int i = 0; i < 4; i++)
        #pragma unroll
        for (int j = 0; j < 4; j++) acc[i][j] = (f32x4){0.f, 0.f, 0.f, 0.f};

    for (int k0 = 0; k0 < 1024; k0 += 32) {
        #pragma unroll
        for (int j = 0; j < 2; j++) {
            const int r = w * 32 + j * 16;
            GLDS16(Ab  + (size_t)(m0 + r + srow) * 1024 + k0 + scol, &As[r * 32]);
            GLDS16(Wto + (size_t)(n0 + r + srow) * 1024 + k0 + scol, &Bs[r * 32]);
        }
        __syncthreads();
        bf16x8 af[4], bf[4];
        #pragma unroll
        for (int rt = 0; rt < 4; rt++)
            af[rt] = *(const bf16x8*)&As[(wr * 64 + rt * 16 + c) * 32 + quad * 8];
        #pragma unroll
        for (int nt = 0; nt < 4; nt++)
            bf[nt] = *(const bf16x8*)&Bs[(wc * 64 + nt * 16 + c) * 32 + quad * 8];
        #pragma unroll
        for (int rt = 0; rt < 4; rt++)
            #pragma unroll
            for (int nt = 0; nt < 4; nt++)
                acc[rt][nt] = __builtin_amdgcn_mfma_f32_16x16x32_bf16(af[rt], bf[nt], acc[rt][nt], 0, 0, 0);
        __syncthreads();
    }
    #pragma unroll
    for (int rt = 0; rt < 4; rt++) {
        #pragma unroll
        for (int reg = 0; reg < 4; reg++) {
            const int m = m0 + wr * 64 + rt * 16 + quad * 4 + reg;
            #pragma unroll
            for (int nt = 0; nt < 4; nt++) {
                const int n = n0 + wc * 64 + nt * 16 + c;
                Out[(size_t)m * 1024 + n] = acc[rt][nt][reg] + bo[n];
            }
        }
    }
}

// ---------------------------------------------------------------------------
// Split-K flash attention. Q pre-scaled (no per-tile mul); ones-row frags
// hoisted out of the K-loop.
// ---------------------------------------------------------------------------
__global__ __launch_bounds__(256)
void attn_part(const unsigned short* __restrict__ Qb, const unsigned short* __restrict__ Kb,
               const unsigned short* __restrict__ Vtb, unsigned short* __restrict__ Ab,
               float* __restrict__ Opart, float* __restrict__ Lpart)
{
    __shared__ unsigned short Ks[64 * 72];      // [key][d], pitch 144B
    __shared__ unsigned short Vs[65 * 72];      // [p][key] + ones row
    __shared__ unsigned short Ps[4 * 16 * 72];  // per-wave P [q][key]

    const int tid = threadIdx.x, w = tid >> 6, lane = tid & 63;
    const int quad = lane >> 4, c = lane & 15;
    const int bh = blockIdx.y;
    const int x = (blockIdx.x < 32) ? (int)blockIdx.x + 16 : (int)blockIdx.x - 32;
    int i, start, len;
    if (x < 32) { i = x + 1;  start = 0;  len = (i < 16) ? i : 16; }
    else        { i = x - 15; start = 16; len = i - 16; }
    const int q0 = (i - 1) * 64;
    const bool complete = (start == 0) && (len == i);
    const size_t base = (size_t)bh * 2048 * 64;

    if (tid < 64) Vs[64 * 72 + tid] = 0x3F80;   // bf16 1.0 ones row
    __syncthreads();
    const bf16x8 on0 = *(const bf16x8*)&Vs[64 * 72 + quad * 8];
    const bf16x8 on1 = *(const bf16x8*)&Vs[64 * 72 + 32 + quad * 8];

    const int qbase = q0 + w * 16;
    const int qrow  = qbase + c;
    const size_t qoff = base + (size_t)qrow * 64;
    const bf16x8 qf0 = *(const bf16x8*)(Qb + qoff + quad * 8);
    const bf16x8 qf1 = *(const bf16x8*)(Qb + qoff + 32 + quad * 8);

    f32x4 O[4], Osum;
    Osum = (f32x4){0.f, 0.f, 0.f, 0.f};
    #pragma unroll
    for (int nt = 0; nt < 4; nt++) O[nt] = (f32x4){0.f, 0.f, 0.f, 0.f};

    const int r0s = tid >> 3, r1s = r0s + 32, c8 = (tid & 7) * 8;

    int k0 = start * 64;
    int4 kreg0 = *(const int4*)(Kb  + base + (size_t)(k0 + r0s) * 64 + c8);
    int4 kreg1 = *(const int4*)(Kb  + base + (size_t)(k0 + r1s) * 64 + c8);
    int4 vreg0 = *(const int4*)(Vtb + base + (size_t)r0s * 2048 + k0 + c8);
    int4 vreg1 = *(const int4*)(Vtb + base + (size_t)r1s * 2048 + k0 + c8);

    unsigned short* Pw = Ps + w * 16 * 72;

    for (int t = 0; t < len; t++, k0 += 64) {
        *(int4*)&Ks[(size_t)r0s * 72 + c8] = kreg0;
        *(int4*)&Ks[(size_t)r1s * 72 + c8] = kreg1;
        *(int4*)&Vs[(size_t)r0s * 72 + c8] = vreg0;
        *(int4*)&Vs[(size_t)r1s * 72 + c8] = vreg1;
        __syncthreads();

        if (t + 1 < len) {
            const int kn = k0 + 64;
            kreg0 = *(const int4*)(Kb  + base + (size_t)(kn + r0s) * 64 + c8);
            kreg1 = *(const int4*)(Kb  + base + (size_t)(kn + r1s) * 64 + c8);
            vreg0 = *(const int4*)(Vtb + base + (size_t)r0s * 2048 + kn + c8);
            vreg1 = *(const int4*)(Vtb + base + (size_t)r1s * 2048 + kn + c8);
        }

        const bool need_mask = (k0 + 63) > qbase;

        #pragma unroll
        for (int nt = 0; nt < 4; nt++) {
            const bf16x8 kf0 = *(const bf16x8*)&Ks[(nt * 16 + c) * 72 + quad * 8];
            const bf16x8 kf1 = *(const bf16x8*)&Ks[(nt * 16 + c) * 72 + 32 + quad * 8];
            f32x4 s4 = (f32x4){0.f, 0.f, 0.f, 0.f};
            s4 = __builtin_amdgcn_mfma_f32_16x16x32_bf16(kf0, qf0, s4, 0, 0, 0);
            s4 = __builtin_amdgcn_mfma_f32_16x16x32_bf16(kf1, qf1, s4, 0, 0, 0);
            const int keyb = k0 + nt * 16 + quad * 4;
            unsigned short u[4];
            #pragma unroll
            for (int reg = 0; reg < 4; reg++) {
                float p = __expf(s4[reg]);            // Q pre-scaled by 0.125
                if (need_mask && (keyb + reg > qrow)) p = 0.f;
                u[reg] = f2bf(p);
            }
            *(int2*)&Pw[c * 72 + nt * 16 + quad * 4] = *(int2*)u;
        }

        const bf16x8 pa0 = *(const bf16x8*)&Pw[c * 72 + quad * 8];
        const bf16x8 pa1 = *(const bf16x8*)&Pw[c * 72 + 32 + quad * 8];
        #pragma unroll
        for (int nt = 0; nt < 4; nt++) {
            const bf16x8 vb0 = *(const bf16x8*)&Vs[(nt * 16 + c) * 72 + quad * 8];
            const bf16x8 vb1 = *(const bf16x8*)&Vs[(nt * 16 + c) * 72 + 32 + quad * 8];
            O[nt] = __builtin_amdgcn_mfma_f32_16x16x32_bf16(pa0, vb0, O[nt], 0, 0, 0);
            O[nt] = __builtin_amdgcn_mfma_f32_16x16x32_bf16(pa1, vb1, O[nt], 0, 0, 0);
        }
        Osum = __builtin_amdgcn_mfma_f32_16x16x32_bf16(pa0, on0, Osum, 0, 0, 0);
        Osum = __builtin_amdgcn_mfma_f32_16x16x32_bf16(pa1, on1, Osum, 0, 0, 0);
        __syncthreads();
    }

    if (complete) {
        const int b = bh >> 4, h = bh & 15;
        #pragma unroll
        for (int reg = 0; reg < 4; reg++) {
            const float inv = 1.0f / Osum[reg];
            const int q = qbase + quad * 4 + reg;
            unsigned short u[4];
            #pragma unroll
            for (int nt = 0; nt < 4; nt++) u[nt] = f2bf(O[nt][reg] * inv);
            unsigned short* dst = Ab + ((size_t)(b * 2048 + q)) * 1024 + h * 64;
            *(int2*)(dst + c * 4) = *(int2*)u;     // sigma: pos c*4+nt
        }
    } else {
        const int pslot = (i - 17) * 2 + (start ? 1 : 0);
        float* Op = Opart + ((size_t)bh * 32 + pslot) * 4096;
        float* Lp = Lpart + ((size_t)bh * 32 + pslot) * 64;
        #pragma unroll
        for (int reg = 0; reg < 4; reg++) {
            const int row = w * 16 + quad * 4 + reg;
            float4 o4 = make_float4(O[0][reg], O[1][reg], O[2][reg], O[3][reg]);
            *(float4*)(Op + (size_t)row * 64 + c * 4) = o4;   // sigma order
            if (c == 0) Lp[row] = Osum[reg];
        }
    }
}

// ---------------------------------------------------------------------------
// Combine two partials: O = O0+O1, normalize, write bf16.
// ---------------------------------------------------------------------------
__global__ __launch_bounds__(256)
void attn_combine(const float* __restrict__ Opart, const float* __restrict__ Lpart,
                  unsigned short* __restrict__ Ab)
{
    const int tid = threadIdx.x;
    const int j = blockIdx.x, bh = blockIdx.y;
    const int q0 = (j + 16) * 64;
    const size_t s0 = ((size_t)bh * 32 + j * 2) * 4096;
    const size_t l0 = ((size_t)bh * 32 + j * 2) * 64;

    __shared__ float linv[64];
    if (tid < 64) linv[tid] = 1.0f / (Lpart[l0 + tid] + Lpart[l0 + 64 + tid]);
    __syncthreads();

    const int row = tid >> 2, col0 = (tid & 3) * 16;
    const float inv = linv[row];
    const int b = bh >> 4, h = bh & 15;
    const int q = q0 + row;
    unsigned short* dst = Ab + ((size_t)(b * 2048 + q)) * 1024 + h * 64 + col0;
    #pragma unroll
    for (int c4 = 0; c4 < 16; c4 += 4) {
        const float4 a  = *(const float4*)(Opart + s0 + (size_t)row * 64 + col0 + c4);
        const float4 bb = *(const float4*)(Opart + s0 + 4096 + (size_t)row * 64 + col0 + c4);
        dst[c4 + 0] = f2bf((a.x + bb.x) * inv);
        dst[c4 + 1] = f2bf((a.y + bb.y) * inv);
        dst[c4 + 2] = f2bf((a.z + bb.z) * inv);
        dst[c4 + 3] = f2bf((a.w + bb.w) * inv);
    }
}

// ---------------------------------------------------------------------------
extern "C" void kernel_launch(void* const* d_in, const int* in_sizes, int n_in,
                              void* d_out, int out_size, void* d_ws, size_t ws_size,
                              hipStream_t stream)
{
    const float* X  = (const float*)d_in[0];
    const float* wq = (const float*)d_in[2];
    const float* bq = (const float*)d_in[3];
    const float* wk = (const float*)d_in[4];
    const float* bk = (const float*)d_in[5];
    const float* wv = (const float*)d_in[6];
    const float* bv = (const float*)d_in[7];
    const float* wo = (const float*)d_in[8];
    const float* bo = (const float*)d_in[9];

    unsigned short* ws = (unsigned short*)d_ws;
    const size_t M1 = 1024 * 1024;
    unsigned short* Xb  = ws;             // 4M elems
    unsigned short* Wtq = Xb  + 4 * M1;   // 1M each
    unsigned short* Wtk = Wtq + M1;
    unsigned short* Wtv = Wtk + M1;
    unsigned short* Wto = Wtv + M1;
    unsigned short* Qb  = Wto + M1;       // 4M each
    unsigned short* Kb  = Qb  + 4 * M1;
    unsigned short* Vtb = Kb  + 4 * M1;   // V^T written directly by qkv_gemm
    unsigned short* Ab  = Vtb + 4 * M1;   // bf16, 4M elems
    float* Opart = (float*)(Ab + 4 * M1); // 16 MB
    float* Lpart = Opart + (size_t)32 * 32 * 4096;

    prep        <<<dim3(16, 16, 12), 256, 0, stream>>>(X, Xb, wq, wk, wv, wo,
                                                       Wtq, Wtk, Wtv, Wto);
    qkv_gemm    <<<dim3(32, 8, 3), 256, 0, stream>>>(Xb, Wtq, Wtk, Wtv, bq, bk, bv,
                                                     Qb, Kb, Vtb);
    attn_part   <<<dim3(48, 32), 256, 0, stream>>>(Qb, Kb, Vtb, Ab, Opart, Lpart);
    attn_combine<<<dim3(16, 32), 256, 0, stream>>>(Opart, Lpart, Ab);
    out_gemm    <<<dim3(32, 8), 256, 0, stream>>>(Ab, Wto, bo, (float*)d_out);
}

// Round 11
// 218.771 us; speedup vs baseline: 1.0558x; 1.0335x over previous
//
#include <hip/hip_runtime.h>
#include <math.h>

typedef short bf16x8 __attribute__((ext_vector_type(8)));
typedef float f32x4  __attribute__((ext_vector_type(4)));

__device__ __forceinline__ unsigned short f2bf(float f) {
    union { float f; unsigned u; } v; v.f = f;
    unsigned r = v.u + 0x7FFFu + ((v.u >> 16) & 1u);   // RNE
    return (unsigned short)(r >> 16);
}

// async global->LDS, 16B per lane, LDS dest = wave-uniform base + lane*16B
#define GLDS16(gp, lp) __builtin_amdgcn_global_load_lds( \
    (const __attribute__((address_space(1))) void*)(gp), \
    (__attribute__((address_space(3))) void*)(lp), 16, 0, 0)

// Head-dim permutation: MFMA-C position (nt*16+c) stored at byte position
// (c*4+nt) within each 64-wide head block. Q,K share pi (dot invariant);
// V/Ab use sigma; Wto compensates. Q additionally pre-scaled by 0.125.

// ---------------------------------------------------------------------------
// prep: z<4 -> W fp32 [k][n] -> Wt bf16 [n][k] (z=3 un-permutes sigma(pi));
//       z>=4 -> X fp32 -> bf16 copy-convert
// ---------------------------------------------------------------------------
__global__ __launch_bounds__(256)
void prep(const float* __restrict__ X, unsigned short* __restrict__ Xb,
          const float* __restrict__ w0, const float* __restrict__ w1,
          const float* __restrict__ w2, const float* __restrict__ w3,
          unsigned short* o0, unsigned short* o1,
          unsigned short* o2, unsigned short* o3)
{
    const int z = blockIdx.z;
    if (z >= 4) {
        const int lb = (z - 4) * 256 + blockIdx.y * 16 + blockIdx.x;
        const size_t t = (size_t)lb * 256 + threadIdx.x;
        const float4 a = *(const float4*)(X + t * 8);
        const float4 b = *(const float4*)(X + t * 8 + 4);
        unsigned short u[8] = { f2bf(a.x), f2bf(a.y), f2bf(a.z), f2bf(a.w),
                                f2bf(b.x), f2bf(b.y), f2bf(b.z), f2bf(b.w) };
        *(int4*)(Xb + t * 8) = *(int4*)u;
        return;
    }
    const float* W; unsigned short* O;
    switch (z) {
        case 0: W = w0; O = o0; break;
        case 1: W = w1; O = o1; break;
        case 2: W = w2; O = o2; break;
        default: W = w3; O = o3; break;
    }
    __shared__ float T[64][65];
    const int tid = threadIdx.x;
    const int n0 = blockIdx.x * 64, k0 = blockIdx.y * 64;
    #pragma unroll
    for (int i = 0; i < 4; i++) {
        const int k = (tid >> 4) + i * 16, n4 = (tid & 15) * 4;
        const float4 v = *(const float4*)(W + (size_t)(k0 + k) * 1024 + n0 + n4);
        T[k][n4] = v.x; T[k][n4+1] = v.y; T[k][n4+2] = v.z; T[k][n4+3] = v.w;
    }
    __syncthreads();
    if (z == 3) {
        #pragma unroll
        for (int i = 0; i < 4; i++) {
            const int n = (tid >> 4) + i * 16, k4 = (tid & 15) * 4;
            unsigned short u[4];
            #pragma unroll
            for (int j = 0; j < 4; j++) {
                const int q = k4 + j;                      // Ab storage pos
                const int p = (q & 3) * 16 + (q >> 2);     // inv sigma
                const int d = (p & 3) * 16 + (p >> 2);     // inv pi
                u[j] = f2bf(T[d][n]);
            }
            *(int2*)(O + (size_t)(n0 + n) * 1024 + k0 + k4) = *(int2*)u;
        }
    } else {
        #pragma unroll
        for (int i = 0; i < 4; i++) {
            const int n = (tid >> 4) + i * 16, k4 = (tid & 15) * 4;
            unsigned short u[4] = { f2bf(T[k4][n]), f2bf(T[k4+1][n]),
                                    f2bf(T[k4+2][n]), f2bf(T[k4+3][n]) };
            *(int2*)(O + (size_t)(n0 + n) * 1024 + k0 + k4) = *(int2*)u;
        }
    }
}

// ---------------------------------------------------------------------------
// QKV GEMM (R10 structure, unchanged): BK=32 m97 staging, RoPE/prescale/
// pi-packed q,k epilogue, coalesced V^T via LDS transpose.
// ---------------------------------------------------------------------------
__global__ __launch_bounds__(256)
void qkv_gemm(const unsigned short* __restrict__ Xb,
              const unsigned short* __restrict__ Wtq, const unsigned short* __restrict__ Wtk,
              const unsigned short* __restrict__ Wtv,
              const float* __restrict__ bq, const float* __restrict__ bk,
              const float* __restrict__ bv,
              unsigned short* __restrict__ Qb, unsigned short* __restrict__ Kb,
              unsigned short* __restrict__ Vtb)
{
    const unsigned short* Wt; const float* bias; unsigned short* Out;
    const int z = blockIdx.z;
    if (z == 0)      { Wt = Wtq; bias = bq; Out = Qb; }
    else if (z == 1) { Wt = Wtk; bias = bk; Out = Kb; }
    else             { Wt = Wtv; bias = bv; Out = Vtb; }

    __shared__ unsigned short Sh[128 * 72];          // 18.4 KB
    unsigned short* As = Sh;                         // 128*32 staging [m][k]
    unsigned short* Bs = Sh + 128 * 32;              // 128*32 staging [n][k]
    unsigned short* T  = Sh;                         // 128*72 epilogue transpose

    const int tid = threadIdx.x, lane = tid & 63, w = tid >> 6;
    const int quad = lane >> 4, c = lane & 15;
    const int wr = w >> 1, wc = w & 1;
    const int m0 = blockIdx.x * 128, n0 = blockIdx.y * 128;
    const int srow = lane >> 2, scol = (lane & 3) * 8;

    f32x4 acc[4][4];
    #pragma unroll
    for (int i = 0; i < 4; i++)
        #pragma unroll
        for (int j = 0; j < 4; j++) acc[i][j] = (f32x4){0.f, 0.f, 0.f, 0.f};

    for (int k0 = 0; k0 < 1024; k0 += 32) {
        #pragma unroll
        for (int j = 0; j < 2; j++) {
            const int r = w * 32 + j * 16;
            GLDS16(Xb + (size_t)(m0 + r + srow) * 1024 + k0 + scol, &As[r * 32]);
            GLDS16(Wt + (size_t)(n0 + r + srow) * 1024 + k0 + scol, &Bs[r * 32]);
        }
        __syncthreads();
        bf16x8 af[4], bf[4];
        #pragma unroll
        for (int rt = 0; rt < 4; rt++)
            af[rt] = *(const bf16x8*)&As[(wr * 64 + rt * 16 + c) * 32 + quad * 8];
        #pragma unroll
        for (int nt = 0; nt < 4; nt++)
            bf[nt] = *(const bf16x8*)&Bs[(wc * 64 + nt * 16 + c) * 32 + quad * 8];
        #pragma unroll
        for (int rt = 0; rt < 4; rt++)
            #pragma unroll
            for (int nt = 0; nt < 4; nt++)
                acc[rt][nt] = __builtin_amdgcn_mfma_f32_16x16x32_bf16(af[rt], bf[nt], acc[rt][nt], 0, 0, 0);
        __syncthreads();
    }

    float bv4[4];
    #pragma unroll
    for (int nt = 0; nt < 4; nt++) bv4[nt] = bias[n0 + wc * 64 + nt * 16 + c];

    if (z == 2) {
        const int b = m0 >> 11, sb = m0 & 2047;
        const int hgbase = n0 >> 6;
        #pragma unroll
        for (int h = 0; h < 2; h++) {
            if (wc == h) {
                #pragma unroll
                for (int rt = 0; rt < 4; rt++)
                    #pragma unroll
                    for (int reg = 0; reg < 4; reg++) {
                        const int s = wr * 64 + rt * 16 + quad * 4 + reg;
                        unsigned short u[4];
                        #pragma unroll
                        for (int nt = 0; nt < 4; nt++)
                            u[nt] = f2bf(acc[rt][nt][reg] + bv4[nt]);
                        *(int2*)&T[s * 72 + c * 4] = *(int2*)u;   // p = c*4+nt (sigma)
                    }
            }
            __syncthreads();
            const int p = tid >> 2, s8 = (tid & 3) * 32;
            unsigned short* dstb = Vtb + ((size_t)(b * 16 + hgbase + h) * 64 + p) * 2048 + sb;
            #pragma unroll
            for (int jj = 0; jj < 32; jj += 8) {
                unsigned short u[8];
                #pragma unroll
                for (int j = 0; j < 8; j++) u[j] = T[(s8 + jj + j) * 72 + p];
                *(int4*)(dstb + s8 + jj) = *(int4*)u;
            }
            __syncthreads();
        }
        return;
    }

    const float kLn = 9.210340371976184f / 32.0f;   // ln(10000)/32
    const float TWO_PI_INV = 0.15915494309189535f;
    const float rv0 = expf(-(float)c * kLn) * TWO_PI_INV;
    const float rv1 = expf(-(float)(c + 16) * kLn) * TWO_PI_INV;
    const float qscale = (z == 0) ? 0.125f : 1.0f;  // fold 1/sqrt(64) into Q

    #pragma unroll
    for (int rt = 0; rt < 4; rt++) {
        #pragma unroll
        for (int reg = 0; reg < 4; reg++) {
            const int m = m0 + wr * 64 + rt * 16 + quad * 4 + reg;
            const int b = m >> 11, s = m & 2047;
            float x0 = acc[rt][0][reg] + bv4[0];
            float x1 = acc[rt][1][reg] + bv4[1];
            float x2 = acc[rt][2][reg] + bv4[2];
            float x3 = acc[rt][3][reg] + bv4[3];
            float r0 = (float)s * rv0;  r0 -= floorf(r0);
            float r1 = (float)s * rv1;  r1 -= floorf(r1);
            const float sn0 = __builtin_amdgcn_sinf(r0);
            const float cs0 = __builtin_amdgcn_cosf(r0);
            const float sn1 = __builtin_amdgcn_sinf(r1);
            const float cs1 = __builtin_amdgcn_cosf(r1);
            const float y0 = (x0 * cs0 - x2 * sn0) * qscale;
            const float y2 = (x0 * sn0 + x2 * cs0) * qscale;
            const float y1 = (x1 * cs1 - x3 * sn1) * qscale;
            const float y3 = (x1 * sn1 + x3 * cs1) * qscale;
            const int h = (n0 + wc * 64) >> 6;
            unsigned short u[4] = { f2bf(y0), f2bf(y1), f2bf(y2), f2bf(y3) };
            unsigned short* dst = Out + ((size_t)(b * 16 + h) * 2048 + s) * 64;
            *(int2*)(dst + c * 4) = *(int2*)u;     // pi: pos c*4+nt
        }
    }
}

// ---------------------------------------------------------------------------
// Output projection GEMM: 64x128 tile, 512 blocks (2/CU). BK=32 m97 staging.
// Wave = 32 rows x 64 cols (acc 2x4).
// ---------------------------------------------------------------------------
__global__ __launch_bounds__(256)
void out_gemm(const unsigned short* __restrict__ Ab, const unsigned short* __restrict__ Wto,
              const float* __restrict__ bo, float* __restrict__ Out)
{
    __shared__ unsigned short As[64 * 32];
    __shared__ unsigned short Bs[128 * 32];
    const int tid = threadIdx.x, lane = tid & 63, w = tid >> 6;
    const int quad = lane >> 4, c = lane & 15;
    const int wr = w >> 1, wc = w & 1;
    const int m0 = blockIdx.x * 64, n0 = blockIdx.y * 128;
    const int srow = lane >> 2, scol = (lane & 3) * 8;

    f32x4 acc[2][4];
    #pragma unroll
    for (int i = 0; i < 2; i++)
        #pragma unroll
        for (int j = 0; j < 4; j++) acc[i][j] = (f32x4){0.f, 0.f, 0.f, 0.f};

    for (int k0 = 0; k0 < 1024; k0 += 32) {
        {
            const int r = w * 16;
            GLDS16(Ab + (size_t)(m0 + r + srow) * 1024 + k0 + scol, &As[r * 32]);
        }
        #pragma unroll
        for (int j = 0; j < 2; j++) {
            const int r = w * 32 + j * 16;
            GLDS16(Wto + (size_t)(n0 + r + srow) * 1024 + k0 + scol, &Bs[r * 32]);
        }
        __syncthreads();
        bf16x8 af[2], bf[4];
        #pragma unroll
        for (int rt = 0; rt < 2; rt++)
            af[rt] = *(const bf16x8*)&As[(wr * 32 + rt * 16 + c) * 32 + quad * 8];
        #pragma unroll
        for (int nt = 0; nt < 4; nt++)
            bf[nt] = *(const bf16x8*)&Bs[(wc * 64 + nt * 16 + c) * 32 + quad * 8];
        #pragma unroll
        for (int rt = 0; rt < 2; rt++)
            #pragma unroll
            for (int nt = 0; nt < 4; nt++)
                acc[rt][nt] = __builtin_amdgcn_mfma_f32_16x16x32_bf16(af[rt], bf[nt], acc[rt][nt], 0, 0, 0);
        __syncthreads();
    }
    #pragma unroll
    for (int rt = 0; rt < 2; rt++) {
        #pragma unroll
        for (int reg = 0; reg < 4; reg++) {
            const int m = m0 + wr * 32 + rt * 16 + quad * 4 + reg;
            #pragma unroll
            for (int nt = 0; nt < 4; nt++) {
                const int n = n0 + wc * 64 + nt * 16 + c;
                Out[(size_t)m * 1024 + n] = acc[rt][nt][reg] + bo[n];
            }
        }
    }
}

// ---------------------------------------------------------------------------
// Split-K flash attention: 512-thread blocks (8 waves), 128 queries/block.
// Each staged 64-key tile serves 128 queries -> staging/barriers halve.
// x in [0,24): x<8 -> q-tile128 ip=9+x chunk0 (tiles 0..15, partial);
// x in [8,16) -> ip=24-x chunk1 (tiles 16.., partial); x>=16 -> ip=24-x
// complete. Heavy chunks first.
// ---------------------------------------------------------------------------
__global__ __launch_bounds__(512)
void attn_part(const unsigned short* __restrict__ Qb, const unsigned short* __restrict__ Kb,
               const unsigned short* __restrict__ Vtb, unsigned short* __restrict__ Ab,
               float* __restrict__ Opart, float* __restrict__ Lpart)
{
    __shared__ unsigned short Ks[64 * 72];      // [key][d], pitch 144B
    __shared__ unsigned short Vs[65 * 72];      // [p][key] + ones row
    __shared__ unsigned short Ps[8 * 16 * 72];  // per-wave P [q][key]

    const int tid = threadIdx.x, w = tid >> 6, lane = tid & 63;
    const int quad = lane >> 4, c = lane & 15;
    const int bh = blockIdx.y;
    const int x = blockIdx.x;
    int ip, start, len;
    if (x < 8)       { ip = 9 + x;  start = 0;  len = 16; }
    else if (x < 16) { ip = 24 - x; start = 16; len = 2 * ip - 16; }
    else             { ip = 24 - x; start = 0;  len = 2 * ip; }
    const int q0 = (ip - 1) * 128;
    const bool complete = (x >= 16);
    const size_t base = (size_t)bh * 2048 * 64;

    if (tid < 64) Vs[64 * 72 + tid] = 0x3F80;   // bf16 1.0 ones row
    __syncthreads();
    const bf16x8 on0 = *(const bf16x8*)&Vs[64 * 72 + quad * 8];
    const bf16x8 on1 = *(const bf16x8*)&Vs[64 * 72 + 32 + quad * 8];

    const int qbase = q0 + w * 16;
    const int qrow  = qbase + c;
    const size_t qoff = base + (size_t)qrow * 64;
    const bf16x8 qf0 = *(const bf16x8*)(Qb + qoff + quad * 8);
    const bf16x8 qf1 = *(const bf16x8*)(Qb + qoff + 32 + quad * 8);

    f32x4 O[4], Osum;
    Osum = (f32x4){0.f, 0.f, 0.f, 0.f};
    #pragma unroll
    for (int nt = 0; nt < 4; nt++) O[nt] = (f32x4){0.f, 0.f, 0.f, 0.f};

    // staging: 512 threads cover 64 rows x 64 elems (16B each) in one shot
    const int rs = tid >> 3, c8 = (tid & 7) * 8;

    int k0 = start * 64;
    int4 kreg = *(const int4*)(Kb  + base + (size_t)(k0 + rs) * 64 + c8);
    int4 vreg = *(const int4*)(Vtb + base + (size_t)rs * 2048 + k0 + c8);

    unsigned short* Pw = Ps + w * 16 * 72;

    for (int t = 0; t < len; t++, k0 += 64) {
        *(int4*)&Ks[(size_t)rs * 72 + c8] = kreg;
        *(int4*)&Vs[(size_t)rs * 72 + c8] = vreg;
        __syncthreads();

        if (t + 1 < len) {
            const int kn = k0 + 64;
            kreg = *(const int4*)(Kb  + base + (size_t)(kn + rs) * 64 + c8);
            vreg = *(const int4*)(Vtb + base + (size_t)rs * 2048 + kn + c8);
        }

        if (k0 <= qbase + 15) {                 // wave-uniform: else fully masked
            const bool need_mask = (k0 + 63) > qbase;
            #pragma unroll
            for (int nt = 0; nt < 4; nt++) {
                const bf16x8 kf0 = *(const bf16x8*)&Ks[(nt * 16 + c) * 72 + quad * 8];
                const bf16x8 kf1 = *(const bf16x8*)&Ks[(nt * 16 + c) * 72 + 32 + quad * 8];
                f32x4 s4 = (f32x4){0.f, 0.f, 0.f, 0.f};
                s4 = __builtin_amdgcn_mfma_f32_16x16x32_bf16(kf0, qf0, s4, 0, 0, 0);
                s4 = __builtin_amdgcn_mfma_f32_16x16x32_bf16(kf1, qf1, s4, 0, 0, 0);
                const int keyb = k0 + nt * 16 + quad * 4;
                unsigned short u[4];
                #pragma unroll
                for (int reg = 0; reg < 4; reg++) {
                    float p = __expf(s4[reg]);            // Q pre-scaled by 0.125
                    if (need_mask && (keyb + reg > qrow)) p = 0.f;
                    u[reg] = f2bf(p);
                }
                *(int2*)&Pw[c * 72 + nt * 16 + quad * 4] = *(int2*)u;
            }
            const bf16x8 pa0 = *(const bf16x8*)&Pw[c * 72 + quad * 8];
            const bf16x8 pa1 = *(const bf16x8*)&Pw[c * 72 + 32 + quad * 8];
            #pragma unroll
            for (int nt = 0; nt < 4; nt++) {
                const bf16x8 vb0 = *(const bf16x8*)&Vs[(nt * 16 + c) * 72 + quad * 8];
                const bf16x8 vb1 = *(const bf16x8*)&Vs[(nt * 16 + c) * 72 + 32 + quad * 8];
                O[nt] = __builtin_amdgcn_mfma_f32_16x16x32_bf16(pa0, vb0, O[nt], 0, 0, 0);
                O[nt] = __builtin_amdgcn_mfma_f32_16x16x32_bf16(pa1, vb1, O[nt], 0, 0, 0);
            }
            Osum = __builtin_amdgcn_mfma_f32_16x16x32_bf16(pa0, on0, Osum, 0, 0, 0);
            Osum = __builtin_amdgcn_mfma_f32_16x16x32_bf16(pa1, on1, Osum, 0, 0, 0);
        }
        __syncthreads();
    }

    if (complete) {
        const int b = bh >> 4, h = bh & 15;
        #pragma unroll
        for (int reg = 0; reg < 4; reg++) {
            const float inv = 1.0f / Osum[reg];
            const int q = qbase + quad * 4 + reg;
            unsigned short u[4];
            #pragma unroll
            for (int nt = 0; nt < 4; nt++) u[nt] = f2bf(O[nt][reg] * inv);
            unsigned short* dst = Ab + ((size_t)(b * 2048 + q)) * 1024 + h * 64;
            *(int2*)(dst + c * 4) = *(int2*)u;     // sigma: pos c*4+nt
        }
    } else {
        const int pslot = (ip - 9) * 2 + (start ? 1 : 0);   // [0,16)
        float* Op = Opart + ((size_t)bh * 16 + pslot) * 8192;
        float* Lp = Lpart + (size_t)bh * 2048 + (size_t)pslot * 128;
        #pragma unroll
        for (int reg = 0; reg < 4; reg++) {
            const int row = w * 16 + quad * 4 + reg;        // [0,128)
            float4 o4 = make_float4(O[0][reg], O[1][reg], O[2][reg], O[3][reg]);
            *(float4*)(Op + (size_t)row * 64 + c * 4) = o4; // sigma order
            if (c == 0) Lp[row] = Osum[reg];
        }
    }
}

// ---------------------------------------------------------------------------
// Combine two partials per (bh, q-tile128 ip=9..16): O=O0+O1, normalize, bf16.
// ---------------------------------------------------------------------------
__global__ __launch_bounds__(256)
void attn_combine(const float* __restrict__ Opart, const float* __restrict__ Lpart,
                  unsigned short* __restrict__ Ab)
{
    const int tid = threadIdx.x;
    const int j = blockIdx.x, bh = blockIdx.y;      // j in [0,8) -> ip = 9+j
    const int q0 = (8 + j) * 128;
    const size_t s0 = ((size_t)bh * 16 + j * 2) * 8192;
    const size_t l0 = (size_t)bh * 2048 + (size_t)j * 2 * 128;

    __shared__ float linv[128];
    if (tid < 128) linv[tid] = 1.0f / (Lpart[l0 + tid] + Lpart[l0 + 128 + tid]);
    __syncthreads();

    const int row = tid >> 1, col0 = (tid & 1) * 32;
    const float inv = linv[row];
    const int b = bh >> 4, h = bh & 15;
    const int q = q0 + row;
    unsigned short* dst = Ab + ((size_t)(b * 2048 + q)) * 1024 + h * 64 + col0;
    #pragma unroll
    for (int c4 = 0; c4 < 32; c4 += 4) {
        const float4 a  = *(const float4*)(Opart + s0 + (size_t)row * 64 + col0 + c4);
        const float4 bb = *(const float4*)(Opart + s0 + 8192 + (size_t)row * 64 + col0 + c4);
        dst[c4 + 0] = f2bf((a.x + bb.x) * inv);
        dst[c4 + 1] = f2bf((a.y + bb.y) * inv);
        dst[c4 + 2] = f2bf((a.z + bb.z) * inv);
        dst[c4 + 3] = f2bf((a.w + bb.w) * inv);
    }
}

// ---------------------------------------------------------------------------
extern "C" void kernel_launch(void* const* d_in, const int* in_sizes, int n_in,
                              void* d_out, int out_size, void* d_ws, size_t ws_size,
                              hipStream_t stream)
{
    const float* X  = (const float*)d_in[0];
    const float* wq = (const float*)d_in[2];
    const float* bq = (const float*)d_in[3];
    const float* wk = (const float*)d_in[4];
    const float* bk = (const float*)d_in[5];
    const float* wv = (const float*)d_in[6];
    const float* bv = (const float*)d_in[7];
    const float* wo = (const float*)d_in[8];
    const float* bo = (const float*)d_in[9];

    unsigned short* ws = (unsigned short*)d_ws;
    const size_t M1 = 1024 * 1024;
    unsigned short* Xb  = ws;             // 4M elems
    unsigned short* Wtq = Xb  + 4 * M1;   // 1M each
    unsigned short* Wtk = Wtq + M1;
    unsigned short* Wtv = Wtk + M1;
    unsigned short* Wto = Wtv + M1;
    unsigned short* Qb  = Wto + M1;       // 4M each
    unsigned short* Kb  = Qb  + 4 * M1;
    unsigned short* Vtb = Kb  + 4 * M1;   // V^T written directly by qkv_gemm
    unsigned short* Ab  = Vtb + 4 * M1;   // bf16, 4M elems
    float* Opart = (float*)(Ab + 4 * M1); // 32*16*8192 fp32 = 16 MB
    float* Lpart = Opart + (size_t)32 * 16 * 8192;  // 64K fp32

    prep        <<<dim3(16, 16, 12), 256, 0, stream>>>(X, Xb, wq, wk, wv, wo,
                                                       Wtq, Wtk, Wtv, Wto);
    qkv_gemm    <<<dim3(32, 8, 3), 256, 0, stream>>>(Xb, Wtq, Wtk, Wtv, bq, bk, bv,
                                                     Qb, Kb, Vtb);
    attn_part   <<<dim3(24, 32), 512, 0, stream>>>(Qb, Kb, Vtb, Ab, Opart, Lpart);
    attn_combine<<<dim3(8, 32), 256, 0, stream>>>(Opart, Lpart, Ab);
    out_gemm    <<<dim3(64, 8), 256, 0, stream>>>(Ab, Wto, bo, (float*)d_out);
}